// Round 1
// baseline (317.623 us; speedup 1.0000x reference)
//
#include <hip/hip_runtime.h>
#include <hip/hip_bf16.h>

#define B_    16
#define N_    4096
#define D_    64
#define QBLK  64
#define KVBLK 64
#define KTILES (N_ / KVBLK)   // 64
#define LDP   72              // padded LDS row stride in bf16 elems (144 B)

typedef __attribute__((ext_vector_type(8))) short short8v;
typedef __attribute__((ext_vector_type(4))) short short4v;
typedef __attribute__((ext_vector_type(4))) float f32x4;

// round-to-nearest-even fp32 -> bf16
__device__ __forceinline__ short f2bf(float x) {
    union { float f; unsigned u; } c; c.f = x;
    unsigned r = c.u + 0x7FFFu + ((c.u >> 16) & 1u);
    return (short)(r >> 16);
}

__global__ __launch_bounds__(256) void attn_fwd(
    const float* __restrict__ Qg, const float* __restrict__ Kg,
    const float* __restrict__ Vg, float* __restrict__ Og)
{
    // K tile row-major [kv][d]; V tile transposed [d][kv] (kv XOR-swizzled);
    // P per-wave [qrow][kv]. Stride 72 bf16 => 2-way bank aliasing (free).
    __shared__ __align__(16) short Kl[KVBLK][LDP];
    __shared__ __align__(16) short Vt[D_][LDP];
    __shared__ __align__(16) short Pl[4][16][LDP];

    const int tid  = threadIdx.x;
    const int w    = tid >> 6;     // wave 0..3
    const int lane = tid & 63;
    const int g    = lane >> 4;    // 0..3
    const int r16  = lane & 15;

    const int bid   = blockIdx.x;
    const int batch = bid >> 6;            // N_/QBLK = 64 q-tiles per batch
    const int q0    = (bid & 63) * QBLK;

    // ---- Q fragments in registers, pre-scaled by log2(e)/sqrt(D) so the
    // whole softmax runs in the exp2 domain (saves a mul per S element).
    // A-frag layout (16x16x32): lane holds A[l%16][8*(l>>4)+i + 32c].
    const float SC = 0.18033688011112042f;  // log2(e)/8
    const float* qrow = Qg + ((size_t)batch * N_ + q0 + w * 16 + r16) * D_;
    short8v qf[2];
    #pragma unroll
    for (int c = 0; c < 2; ++c) {
        const f32x4 a = *(const f32x4*)(qrow + 32 * c + 8 * g);
        const f32x4 b = *(const f32x4*)(qrow + 32 * c + 8 * g + 4);
        short8v f;
        f[0] = f2bf(a[0] * SC); f[1] = f2bf(a[1] * SC);
        f[2] = f2bf(a[2] * SC); f[3] = f2bf(a[3] * SC);
        f[4] = f2bf(b[0] * SC); f[5] = f2bf(b[1] * SC);
        f[6] = f2bf(b[2] * SC); f[7] = f2bf(b[3] * SC);
        qf[c] = f;
    }

    // Accumulators: o[dblk][i] covers out row (4g+i), col (16*dblk + r16).
    f32x4 o[4];
    #pragma unroll
    for (int dblk = 0; dblk < 4; ++dblk) o[dblk] = (f32x4){0.f, 0.f, 0.f, 0.f};
    float m_i[4] = {-INFINITY, -INFINITY, -INFINITY, -INFINITY};
    float l_i[4] = {0.f, 0.f, 0.f, 0.f};

    const float* kbase = Kg + (size_t)batch * N_ * D_;
    const float* vbase = Vg + (size_t)batch * N_ * D_;

    for (int kt = 0; kt < KTILES; ++kt) {
        const int kv0 = kt * KVBLK;

        // ---- stage K (row-major) and V (transposed, swizzled) into LDS ----
        // Thread t, pass j reads flat elems [j*1024 + 4t, +4): fully coalesced
        // 1 KiB/wave/instr; 64x64 tile in 4 passes.
        #pragma unroll
        for (int j = 0; j < 4; ++j) {
            const int e   = j * 1024 + tid * 4;
            const int row = e >> 6;   // kv within tile
            const int col = e & 63;   // d
            const f32x4 kq = *(const f32x4*)(kbase + (size_t)(kv0 + row) * D_ + col);
            short4v ks;
            ks[0] = f2bf(kq[0]); ks[1] = f2bf(kq[1]);
            ks[2] = f2bf(kq[2]); ks[3] = f2bf(kq[3]);
            *(short4v*)&Kl[row][col] = ks;
            const f32x4 vq = *(const f32x4*)(vbase + (size_t)(kv0 + row) * D_ + col);
            #pragma unroll
            for (int u = 0; u < 4; ++u) {
                const int d = col + u;
                // kv XOR-swizzle in bits>=3: keeps 8-elem read vectors
                // contiguous, spreads transpose-write banks.
                Vt[d][row ^ (((d >> 2) & 7) << 3)] = f2bf(vq[u]);
            }
        }
        __syncthreads();

        // ---- S = (Q*SC) K^T  (16 q-rows x 64 kv per wave) ----
        // B-frag: lane holds K[r16+16n][32c + 8g + i] (contiguous bf16x8).
        f32x4 s[4];
        #pragma unroll
        for (int n = 0; n < 4; ++n) s[n] = (f32x4){0.f, 0.f, 0.f, 0.f};
        #pragma unroll
        for (int c = 0; c < 2; ++c) {
            #pragma unroll
            for (int n = 0; n < 4; ++n) {
                const short8v kf = *(const short8v*)&Kl[r16 + 16 * n][32 * c + 8 * g];
                s[n] = __builtin_amdgcn_mfma_f32_16x16x32_bf16(qf[c], kf, s[n], 0, 0, 0);
            }
        }

        // ---- online softmax in exp2 domain; D row = 4g+i, col = r16+16n ----
        f32x4 mx;
        #pragma unroll
        for (int i = 0; i < 4; ++i)
            mx[i] = fmaxf(fmaxf(s[0][i], s[1][i]), fmaxf(s[2][i], s[3][i]));
        #pragma unroll
        for (int off = 1; off <= 8; off <<= 1) {
            #pragma unroll
            for (int i = 0; i < 4; ++i)
                mx[i] = fmaxf(mx[i], __shfl_xor(mx[i], off));
        }
        float rs[4];
        #pragma unroll
        for (int i = 0; i < 4; ++i) {
            const float mn = fmaxf(m_i[i], mx[i]);
            rs[i] = exp2f(m_i[i] - mn);   // first tile: exp2(-inf) = 0
            m_i[i] = mn;
            l_i[i] *= rs[i];
        }
        #pragma unroll
        for (int dblk = 0; dblk < 4; ++dblk) {
            #pragma unroll
            for (int i = 0; i < 4; ++i) o[dblk][i] *= rs[i];
        }
        f32x4 ps;
        #pragma unroll
        for (int n = 0; n < 4; ++n) {
            #pragma unroll
            for (int i = 0; i < 4; ++i) {
                const float p = exp2f(s[n][i] - m_i[i]);
                s[n][i] = p;
            }
        }
        #pragma unroll
        for (int i = 0; i < 4; ++i)
            ps[i] = (s[0][i] + s[1][i]) + (s[2][i] + s[3][i]);
        #pragma unroll
        for (int off = 1; off <= 8; off <<= 1) {
            #pragma unroll
            for (int i = 0; i < 4; ++i) ps[i] += __shfl_xor(ps[i], off);
        }
        #pragma unroll
        for (int i = 0; i < 4; ++i) l_i[i] += ps[i];

        // ---- P -> LDS (per-wave buffer; same-wave RAW, no barrier) ----
        #pragma unroll
        for (int n = 0; n < 4; ++n) {
            #pragma unroll
            for (int i = 0; i < 4; ++i)
                Pl[w][4 * g + i][r16 + 16 * n] = f2bf(s[n][i]);
        }

        // ---- O += P V ----
        // A-frag: P[r16][32c+8g+i]; B-frag: V^T read Vt[16dblk+r16][kv..].
        #pragma unroll
        for (int c = 0; c < 2; ++c) {
            const short8v pf = *(const short8v*)&Pl[w][r16][32 * c + 8 * g];
            #pragma unroll
            for (int dblk = 0; dblk < 4; ++dblk) {
                const int d   = 16 * dblk + r16;
                const int kvs = (32 * c + 8 * g) ^ (((d >> 2) & 7) << 3);
                const short8v vf = *(const short8v*)&Vt[d][kvs];
                o[dblk] = __builtin_amdgcn_mfma_f32_16x16x32_bf16(pf, vf, o[dblk], 0, 0, 0);
            }
        }
        __syncthreads();   // protect Kl/Vt before next tile's staging
    }

    // ---- epilogue: normalize and store ----
    float inv[4];
    #pragma unroll
    for (int i = 0; i < 4; ++i) inv[i] = 1.0f / l_i[i];
    float* ob = Og + ((size_t)batch * N_ + q0 + w * 16) * D_;
    #pragma unroll
    for (int dblk = 0; dblk < 4; ++dblk) {
        #pragma unroll
        for (int i = 0; i < 4; ++i)
            ob[(size_t)(4 * g + i) * D_ + 16 * dblk + r16] = o[dblk][i] * inv[i];
    }
}

extern "C" void kernel_launch(void* const* d_in, const int* in_sizes, int n_in,
                              void* d_out, int out_size, void* d_ws, size_t ws_size,
                              hipStream_t stream) {
    const float* Qg = (const float*)d_in[0];
    const float* Kg = (const float*)d_in[1];
    const float* Vg = (const float*)d_in[2];
    // d_in[3] (masking) is a no-op in the reference.
    float* Og = (float*)d_out;
    dim3 grid(B_ * (N_ / QBLK));   // 1024 blocks
    dim3 block(256);               // 4 waves
    attn_fwd<<<grid, block, 0, stream>>>(Qg, Kg, Vg, Og);
}

// Round 2
// 175.677 us; speedup vs baseline: 1.8080x; 1.8080x over previous
//
#include <hip/hip_runtime.h>
#include <hip/hip_bf16.h>

#define B_    16
#define N_    4096
#define D_    64
#define QBLK  64
#define KVBLK 64
#define KTILES (N_ / KVBLK)   // 64

typedef __attribute__((ext_vector_type(8))) short short8v;
typedef __attribute__((ext_vector_type(4))) short short4v;
typedef __attribute__((ext_vector_type(4))) float f32x4;

// round-to-nearest-even fp32 -> bf16
__device__ __forceinline__ short f2bf(float x) {
    union { float f; unsigned u; } c; c.f = x;
    unsigned r = c.u + 0x7FFFu + ((c.u >> 16) & 1u);
    return (short)(r >> 16);
}

#define GLDS16(g, l)                                                      \
    __builtin_amdgcn_global_load_lds(                                     \
        (const __attribute__((address_space(1))) void*)(g),               \
        (__attribute__((address_space(3))) void*)(l), 16, 0, 0)

// ---- pre-pass 1: K fp32 -> bf16, row-major [B*N][64], columns XOR-swizzled
// within each row by ((n&7)<<3) elements so the attention kernel's linear
// global_load_lds staging + swizzled ds_read_b128 is bank-conflict-free.
__global__ __launch_bounds__(256) void conv_k(const float* __restrict__ K,
                                              short* __restrict__ Kp) {
    const int idx = blockIdx.x * 256 + threadIdx.x;   // one 8-elem chunk
    const int n   = idx >> 3;                         // global row b*N+n
    const int c8  = (idx & 7) << 3;
    const float* src = K + (size_t)n * D_ + c8;
    const f32x4 a = *(const f32x4*)src;
    const f32x4 b = *(const f32x4*)(src + 4);
    short8v o;
    o[0] = f2bf(a[0]); o[1] = f2bf(a[1]); o[2] = f2bf(a[2]); o[3] = f2bf(a[3]);
    o[4] = f2bf(b[0]); o[5] = f2bf(b[1]); o[6] = f2bf(b[2]); o[7] = f2bf(b[3]);
    const int cs = c8 ^ ((n & 7) << 3);
    *(short8v*)(Kp + (size_t)n * D_ + cs) = o;
}

// ---- pre-pass 2: V fp32 [B][N][64] -> bf16 transposed [B][64][N], with the
// kv index XOR-swizzled by ((d&7)<<3) within each 64-wide tile.
__global__ __launch_bounds__(256) void conv_v(const float* __restrict__ V,
                                              short* __restrict__ Vp) {
    __shared__ short Tl[64][68];
    const int b  = blockIdx.x >> 6;
    const int n0 = (blockIdx.x & 63) * 64;
    const int t  = threadIdx.x;
    const int r  = t >> 2;              // n within tile
    const int c0 = (t & 3) * 16;        // d base
    const float* src = V + ((size_t)b * N_ + n0 + r) * D_ + c0;
    const f32x4 v0 = *(const f32x4*)(src);
    const f32x4 v1 = *(const f32x4*)(src + 4);
    const f32x4 v2 = *(const f32x4*)(src + 8);
    const f32x4 v3 = *(const f32x4*)(src + 12);
    short8v lo, hi;
    lo[0]=f2bf(v0[0]); lo[1]=f2bf(v0[1]); lo[2]=f2bf(v0[2]); lo[3]=f2bf(v0[3]);
    lo[4]=f2bf(v1[0]); lo[5]=f2bf(v1[1]); lo[6]=f2bf(v1[2]); lo[7]=f2bf(v1[3]);
    hi[0]=f2bf(v2[0]); hi[1]=f2bf(v2[1]); hi[2]=f2bf(v2[2]); hi[3]=f2bf(v2[3]);
    hi[4]=f2bf(v3[0]); hi[5]=f2bf(v3[1]); hi[6]=f2bf(v3[2]); hi[7]=f2bf(v3[3]);
    *(short8v*)&Tl[r][c0]     = lo;
    *(short8v*)&Tl[r][c0 + 8] = hi;
    __syncthreads();
    const int d  = t >> 2;
    const int nb = (t & 3) * 16;        // n_local base
    const int s  = (d & 7) << 3;
    short8v o0, o1;
    #pragma unroll
    for (int j = 0; j < 8; ++j) {
        o0[j] = Tl[nb + j][d];
        o1[j] = Tl[nb + 8 + j][d];
    }
    short* dst = Vp + ((size_t)b * D_ + d) * N_ + n0;
    *(short8v*)(dst + (nb ^ s))       = o0;
    *(short8v*)(dst + ((nb + 8) ^ s)) = o1;
}

// ---- attention: flash, swapped operands so softmax is lane-local.
// S^T = mfma(K,Q): lane holds S[q=r16][kv=16n+4g+reg].
// O^T = mfma(V^T,P): lane holds O[q=r16][d=16dt+4g+reg].
__global__ __launch_bounds__(256) void attn_fwd(
    const float* __restrict__ Qg, const short* __restrict__ Kp,
    const short* __restrict__ Vp, float* __restrict__ Og)
{
    __shared__ __align__(16) short Kl[KVBLK][D_];    // swizzled rows (8 KB)
    __shared__ __align__(16) short Vl[D_][KVBLK];    // row=d, swizzled (8 KB)
    __shared__ __align__(16) short Pl[4][16][72];    // per-wave P (9 KB)

    const int tid  = threadIdx.x;
    const int w    = tid >> 6;
    const int lane = tid & 63;
    const int g    = lane >> 4;
    const int r16  = lane & 15;

    const int batch = blockIdx.x >> 6;
    const int q0    = (blockIdx.x & 63) * QBLK;

    // Q B-fragment: lane holds Q[q=r16][32c+8g+i], pre-scaled by log2(e)/8.
    const float SC = 0.18033688011112042f;
    const float* qrow = Qg + ((size_t)batch * N_ + q0 + w * 16 + r16) * D_;
    short8v qf[2];
    #pragma unroll
    for (int c = 0; c < 2; ++c) {
        const f32x4 a = *(const f32x4*)(qrow + 32 * c + 8 * g);
        const f32x4 b = *(const f32x4*)(qrow + 32 * c + 8 * g + 4);
        short8v f;
        f[0] = f2bf(a[0] * SC); f[1] = f2bf(a[1] * SC);
        f[2] = f2bf(a[2] * SC); f[3] = f2bf(a[3] * SC);
        f[4] = f2bf(b[0] * SC); f[5] = f2bf(b[1] * SC);
        f[6] = f2bf(b[2] * SC); f[7] = f2bf(b[3] * SC);
        qf[c] = f;
    }

    f32x4 o[4];
    #pragma unroll
    for (int dt = 0; dt < 4; ++dt) o[dt] = (f32x4){0.f, 0.f, 0.f, 0.f};
    float m = -INFINITY, l = 0.f;

    const short* kbase = Kp + (size_t)batch * N_ * D_;        // tiles = 8 KB contig
    const short* vbase = Vp + (size_t)batch * D_ * (size_t)N_;
    const int    swz   = (r16 & 7) << 3;

    for (int kt = 0; kt < KTILES; ++kt) {
        const int kv0 = kt * KVBLK;

        // ---- stage K,V via global_load_lds (16B/lane, linear LDS dest) ----
        #pragma unroll
        for (int j = 0; j < 2; ++j) {
            const short* gk = kbase + (size_t)kv0 * D_ + w * 1024 + j * 512 + lane * 8;
            GLDS16(gk, (short*)Kl + w * 1024 + j * 512);
            const int dr = w * 16 + j * 8 + (lane >> 3);
            const short* gv = vbase + (size_t)dr * N_ + kv0 + (lane & 7) * 8;
            GLDS16(gv, (short*)Vl + w * 1024 + j * 512);
        }
        __syncthreads();

        // ---- S^T = K · Q^T (lane-local q-row) ----
        f32x4 st[4];
        #pragma unroll
        for (int n = 0; n < 4; ++n) st[n] = (f32x4){0.f, 0.f, 0.f, 0.f};
        #pragma unroll
        for (int c = 0; c < 2; ++c) {
            #pragma unroll
            for (int n = 0; n < 4; ++n) {
                const short8v kf =
                    *(const short8v*)&Kl[r16 + 16 * n][(32 * c + 8 * g) ^ swz];
                st[n] = __builtin_amdgcn_mfma_f32_16x16x32_bf16(kf, qf[c], st[n], 0, 0, 0);
            }
        }

        // ---- online softmax (exp2 domain), one q-row per lane ----
        float mx = st[0][0];
        #pragma unroll
        for (int n = 0; n < 4; ++n)
            #pragma unroll
            for (int i = 0; i < 4; ++i) mx = fmaxf(mx, st[n][i]);
        mx = fmaxf(mx, __shfl_xor(mx, 16));
        mx = fmaxf(mx, __shfl_xor(mx, 32));
        const float mn = fmaxf(m, mx);
        const float rs = exp2f(m - mn);     // first tile: exp2(-inf)=0
        m = mn;
        float sum = 0.f;
        #pragma unroll
        for (int n = 0; n < 4; ++n) {
            #pragma unroll
            for (int i = 0; i < 4; ++i) {
                const float p = exp2f(st[n][i] - mn);
                st[n][i] = p;
                sum += p;
            }
        }
        sum += __shfl_xor(sum, 16);
        sum += __shfl_xor(sum, 32);
        l = l * rs + sum;
        #pragma unroll
        for (int dt = 0; dt < 4; ++dt)
            #pragma unroll
            for (int i = 0; i < 4; ++i) o[dt][i] *= rs;

        // ---- P -> per-wave LDS (packed b64 writes; same-wave RAW) ----
        #pragma unroll
        for (int n = 0; n < 4; ++n) {
            short4v pk;
            pk[0] = f2bf(st[n][0]); pk[1] = f2bf(st[n][1]);
            pk[2] = f2bf(st[n][2]); pk[3] = f2bf(st[n][3]);
            *(short4v*)&Pl[w][r16][4 * g + 16 * n] = pk;
        }

        // ---- O^T += V^T · P^T ----
        #pragma unroll
        for (int c = 0; c < 2; ++c) {
            const short8v pf = *(const short8v*)&Pl[w][r16][8 * g + 32 * c];
            #pragma unroll
            for (int dt = 0; dt < 4; ++dt) {
                const short8v vf =
                    *(const short8v*)&Vl[16 * dt + r16][(8 * g + 32 * c) ^ swz];
                o[dt] = __builtin_amdgcn_mfma_f32_16x16x32_bf16(vf, pf, o[dt], 0, 0, 0);
            }
        }
        __syncthreads();   // protect Kl/Vl before next tile's staging
    }

    // ---- epilogue: lane owns row q=r16 -> coalesced f32x4 stores ----
    const float inv = 1.0f / l;
    float* ob = Og + ((size_t)batch * N_ + q0 + w * 16 + r16) * D_;
    #pragma unroll
    for (int dt = 0; dt < 4; ++dt) {
        f32x4 r = o[dt];
        r[0] *= inv; r[1] *= inv; r[2] *= inv; r[3] *= inv;
        *(f32x4*)(ob + 16 * dt + 4 * g) = r;
    }
}

extern "C" void kernel_launch(void* const* d_in, const int* in_sizes, int n_in,
                              void* d_out, int out_size, void* d_ws, size_t ws_size,
                              hipStream_t stream) {
    const float* Qg = (const float*)d_in[0];
    const float* Kg = (const float*)d_in[1];
    const float* Vg = (const float*)d_in[2];
    // d_in[3] (masking) is a no-op in the reference.
    float* Og = (float*)d_out;

    short* Kp = (short*)d_ws;                              // 8.4 MB
    short* Vp = Kp + (size_t)B_ * N_ * D_;                 // 8.4 MB

    conv_k<<<dim3(B_ * N_ * 8 / 256), dim3(256), 0, stream>>>(Kg, Kp);
    conv_v<<<dim3(B_ * (N_ / 64)), dim3(256), 0, stream>>>(Vg, Vp);
    attn_fwd<<<dim3(B_ * (N_ / QBLK)), dim3(256), 0, stream>>>(Qg, Kp, Vp, Og);
}